// Round 11
// baseline (137.596 us; speedup 1.0000x reference)
//
#include <hip/hip_runtime.h>
#include <stdint.h>

#define HIDDEN 2048
#define EXPERTS 64
#define T_TOTAL 8192

// ================= GEMM: split-K, global_load_lds staged, 8x8 micro-tile =================
// Block: 256 thr (4 waves), BM=256 rows x 64 experts, BK=16. Thread: rg=t>>3 (0..31) ->
// rows rg*8..+7, eg=t&7 -> experts eg*8..+7. nsplit=32 -> grid 32x32=1024 = 4 blocks/CU
// exactly; LDS 40 KB = 4 blocks/CU exactly -> 16 waves/CU = 4/SIMD (R10: 2/SIMD exposed
// LDS latency; this is the fix). __launch_bounds__(256,4) keeps VGPR <= 128; inner loop
// restructured (a4 loaded per-row just before use) so live regs ~95 -> no spill.
// A XOR-swizzle key (row>>3)&3 == reader rg&3 (R8 algebra); 2-way b128 aliasing measured
// free (R10: 0 conflicts). W linear.
#define BM 256
#define BK 16

#define GLOAD16(g, l) __builtin_amdgcn_global_load_lds(                        \
        (const __attribute__((address_space(1))) unsigned int*)(g),            \
        (__attribute__((address_space(3))) unsigned int*)(l), 16, 0, 0)
#define FENCE() asm volatile("" ::: "memory")

template <int KS>
__global__ __launch_bounds__(256, 4) void snn_gemm_sk(
        const float* __restrict__ A, const float* __restrict__ W,
        float* __restrict__ P) {
    __shared__ float As[2][BM * BK];        // 2 x 16 KB
    __shared__ float Ws[2][BK * EXPERTS];   // 2 x 4 KB

    const int t    = threadIdx.x;           // 0..255
    const int wv   = t >> 6;                // 0..3
    const int rg   = t >> 3;                // 0..31 : rows rg*8..rg*8+7
    const int eg   = t & 7;                 // 0..7  : experts eg*8..eg*8+7
    const long row0 = (long)blockIdx.x * BM;
    const int  k0   = blockIdx.y * KS;
    float* Pout = P + (long)blockIdx.y * ((long)T_TOTAL * EXPERTS);

    // ---- staging geometry ----
    // A: 4 rounds of 256 lanes x 16B. Round p, LDS word o = p*1024 + t*4:
    //   row = p*64 + (t>>2), colblk = t&3. Stored value = A[row][colblk ^ ((row>>3)&3)]
    //   (pre-swizzled global source; (row>>3)&3 == rg&3 of the reader for rows rg*8+i).
    const float* aSrc[4];
#pragma unroll
    for (int p = 0; p < 4; ++p) {
        const int row = p * 64 + (t >> 2);
        const int cb  = (t & 3) ^ ((row >> 3) & 3);
        aSrc[p] = &A[(row0 + row) * HIDDEN + k0 + cb * 4];
    }
    // W: 1 round. LDS word o = t*4: k = t>>4, e-word = (t&15)*4. Linear both sides.
    const float* wSrc = &W[(long)(k0 + (t >> 4)) * EXPERTS + (t & 15) * 4];

    auto stage = [&](int tile, int buf) {
        const int  aoff = tile * BK;
        const long woff = (long)tile * BK * EXPERTS;
#pragma unroll
        for (int p = 0; p < 4; ++p)
            GLOAD16(aSrc[p] + aoff, &As[buf][p * 1024 + wv * 256]);   // +lane*16B by HW
        GLOAD16(wSrc + woff, &Ws[buf][wv * 256]);
    };

    float acc[8][8];
#pragma unroll
    for (int i = 0; i < 8; ++i)
#pragma unroll
        for (int j = 0; j < 8; ++j) acc[i][j] = 0.0f;

    stage(0, 0);

    constexpr int NTILE = KS / BK;
    int buf = 0;
    for (int tile = 0; tile < NTILE; ++tile) {
        if (tile + 1 < NTILE) {
            stage(tile + 1, buf ^ 1);
            asm volatile("s_waitcnt vmcnt(5)" ::: "memory");   // current tile landed; next 5 in flight
        } else {
            asm volatile("s_waitcnt vmcnt(0)" ::: "memory");
        }
        __builtin_amdgcn_s_barrier();
        FENCE();

        const float* ab = &As[buf][0];
        const float* wb = &Ws[buf][0];
        const int swz = rg & 3;   // == (row>>3)&3 for rows rg*8+i, i<8
#pragma unroll
        for (int q = 0; q < BK / 4; ++q) {
            const int qs = (q ^ swz) * 4;   // LDS slot holding true cols q*4..q*4+3
            // W quad for this q (8 regs, live across the i-loop)
            float4 w0[4], w1[4];
#pragma unroll
            for (int ki = 0; ki < 4; ++ki) {
                w0[ki] = *reinterpret_cast<const float4*>(&wb[(q * 4 + ki) * EXPERTS + eg * 8]);
                w1[ki] = *reinterpret_cast<const float4*>(&wb[(q * 4 + ki) * EXPERTS + eg * 8 + 4]);
            }
            // per-row A load right before its fmas: short a4 live ranges, ~95 live regs
#pragma unroll
            for (int i = 0; i < 8; ++i) {
                const float4 a4 = *reinterpret_cast<const float4*>(&ab[(rg * 8 + i) * BK + qs]);
#pragma unroll
                for (int ki = 0; ki < 4; ++ki) {   // k ascending: q outer, ki inner
                    const float av = (&a4.x)[ki];
                    acc[i][0] = fmaf(av, w0[ki].x, acc[i][0]);
                    acc[i][1] = fmaf(av, w0[ki].y, acc[i][1]);
                    acc[i][2] = fmaf(av, w0[ki].z, acc[i][2]);
                    acc[i][3] = fmaf(av, w0[ki].w, acc[i][3]);
                    acc[i][4] = fmaf(av, w1[ki].x, acc[i][4]);
                    acc[i][5] = fmaf(av, w1[ki].y, acc[i][5]);
                    acc[i][6] = fmaf(av, w1[ki].z, acc[i][6]);
                    acc[i][7] = fmaf(av, w1[ki].w, acc[i][7]);
                }
            }
        }
        FENCE();
        __builtin_amdgcn_s_barrier();   // all waves done with buf before restage
        buf ^= 1;
    }

#pragma unroll
    for (int i = 0; i < 8; ++i) {
        float* base = &Pout[(row0 + rg * 8 + i) * EXPERTS + eg * 8];
        *reinterpret_cast<float4*>(base)     = make_float4(acc[i][0], acc[i][1], acc[i][2], acc[i][3]);
        *reinterpret_cast<float4*>(base + 4) = make_float4(acc[i][4], acc[i][5], acc[i][6], acc[i][7]);
    }
}

// ---- fixed-order split-K combine (template-unrolled: loads issued in parallel) ----
template <int NS>
__global__ __launch_bounds__(256) void snn_combine(const float* __restrict__ P,
                                                   float* __restrict__ cur) {
    const long i = (long)blockIdx.x * 256 + threadIdx.x;   // float4 index
    const float4* p = reinterpret_cast<const float4*>(P);
    float4 s = p[i];
#pragma unroll
    for (int k = 1; k < NS; ++k) {
        const float4 v = p[i + (long)k * (T_TOTAL * EXPERTS / 4)];
        s.x += v.x; s.y += v.y; s.z += v.z; s.w += v.w;
    }
    reinterpret_cast<float4*>(cur)[i] = s;
}

// ========= Scan: zero-sync overlap (warm-up 256 steps) + fused softmax =========
// Block w computes steps [w*128-256, w*128+128) from zero state; 0.9^256 forgetting
// makes the output-window state exact (whp bitwise). No flags/states/fences.
#define NCHUNK 64
#define CSTEPS (T_TOTAL / NCHUNK)   // 128
#define WARM   256

template <bool STORE>
__device__ __forceinline__ void lif_chunk(const float (&cbuf)[32], float* __restrict__ smp,
                                          int orow, int e, float& mp, float& refr) {
#pragma clang fp contract(off)
#pragma unroll
    for (int j = 0; j < 32; ++j) {
        const float term   = (refr <= 0.0f) ? cbuf[j] : 0.0f;
        const float mp_pre = mp * 0.9f + term;
        if constexpr (STORE) smp[(orow + j) * EXPERTS + e] = mp_pre;
        const bool spike = mp_pre > 1.0f;
        mp = spike ? 0.0f : mp_pre;
        const float rdec = fmaxf(refr - 0.1f, 0.0f);
        refr = spike ? 1.0f : rdec;
    }
}

__global__ __launch_bounds__(256) void snn_scan_ov(const float* __restrict__ cur,
                                                   float* __restrict__ out) {
    __shared__ float smp[CSTEPS * EXPERTS];   // 32 KB
    const int tid = threadIdx.x;
    const int w   = blockIdx.x;

    if (tid < 64) {
        const int e     = tid;
        const int t0abs = w * CSTEPS;
        const int s0    = (t0abs >= WARM) ? (t0abs - WARM) : 0;
        const int nwarm = t0abs - s0;              // 0, 128 or 256 (mult of 32)
        const int cwarm = nwarm >> 5;
        const int nc    = cwarm + (CSTEPS >> 5);   // 4, 8 or 12 (even)
        const float* cb = cur + (long)s0 * EXPERTS + e;

        float mp = 0.0f, refr = 0.0f;
        float bufA[32], bufB[32];
#pragma unroll
        for (int j = 0; j < 32; ++j) bufA[j] = cb[j * EXPERTS] * 0.1f;

        for (int c2 = 0; c2 < nc; c2 += 2) {
            if (c2 + 1 < nc)
#pragma unroll
                for (int j = 0; j < 32; ++j) bufB[j] = cb[((c2 + 1) * 32 + j) * EXPERTS] * 0.1f;
            if (c2 >= cwarm) lif_chunk<true >(bufA, smp, c2 * 32 - nwarm, e, mp, refr);
            else             lif_chunk<false>(bufA, smp, 0, e, mp, refr);
            if (c2 + 2 < nc)
#pragma unroll
                for (int j = 0; j < 32; ++j) bufA[j] = cb[((c2 + 2) * 32 + j) * EXPERTS] * 0.1f;
            if (c2 + 1 >= cwarm) lif_chunk<true >(bufB, smp, (c2 + 1) * 32 - nwarm, e, mp, refr);
            else                 lif_chunk<false>(bufB, smp, 0, e, mp, refr);
        }
    }
    __syncthreads();

    // ---- fused routing softmax: wave wvid handles rows wvid*32 .. +31 ----
    const int lane = tid & 63;
    const int wvid = tid >> 6;
    const float em1 = expf(-1.0f);
#pragma unroll 4
    for (int r = wvid * 32; r < wvid * 32 + 32; ++r) {
        const float v = smp[r * EXPERTS + lane];
        const bool spike = v > 1.0f;
        const unsigned long long ball = __ballot(spike);
        float res;
        if (ball != 0ull) {
            const int n = __popcll(ball);
            const float denom = (float)n + (float)(EXPERTS - n) * em1;
            res = spike ? (1.0f / denom) : (em1 / denom);
        } else {
            float m = v;
#pragma unroll
            for (int off = 32; off >= 1; off >>= 1)
                m = fmaxf(m, __shfl_xor(m, off, 64));
            const float p = expf(v - m);
            float s = p;
#pragma unroll
            for (int off = 32; off >= 1; off >>= 1)
                s += __shfl_xor(s, off, 64);
            res = p / s;
        }
        out[((long)w * CSTEPS + r) * EXPERTS + lane] = res;
    }
}

// ---------------------------------------------------------------------------
extern "C" void kernel_launch(void* const* d_in, const int* in_sizes, int n_in,
                              void* d_out, int out_size, void* d_ws, size_t ws_size,
                              hipStream_t stream) {
    const float* hs = (const float*)d_in[0];   // [4,2048,2048] f32
    const float* w  = (const float*)d_in[1];   // [2048,64] f32
    float* out = (float*)d_out;                // [4,2048,64] f32

    char*  ws   = (char*)d_ws;
    float* cur  = (float*)(ws + (1u << 20));   // 2 MB @ 1 MB
    float* part = (float*)(ws + (4u << 20));   // up to 32 x 2 MB @ 4 MB

    const size_t slab = (size_t)T_TOTAL * EXPERTS * sizeof(float);   // 2 MB

    if (ws_size >= (4u << 20) + 32 * slab) {            // 68 MB (R10 evidence: ws ~262 MB)
        snn_gemm_sk<HIDDEN / 32><<<dim3(T_TOTAL / BM, 32), dim3(256), 0, stream>>>(hs, w, part);
        snn_combine<32><<<dim3(T_TOTAL * EXPERTS / 4 / 256), dim3(256), 0, stream>>>(part, cur);
    } else if (ws_size >= (4u << 20) + 16 * slab) {
        snn_gemm_sk<HIDDEN / 16><<<dim3(T_TOTAL / BM, 16), dim3(256), 0, stream>>>(hs, w, part);
        snn_combine<16><<<dim3(T_TOTAL * EXPERTS / 4 / 256), dim3(256), 0, stream>>>(part, cur);
    } else if (ws_size >= (4u << 20) + 8 * slab) {
        snn_gemm_sk<HIDDEN / 8><<<dim3(T_TOTAL / BM, 8), dim3(256), 0, stream>>>(hs, w, part);
        snn_combine<8><<<dim3(T_TOTAL * EXPERTS / 4 / 256), dim3(256), 0, stream>>>(part, cur);
    } else {
        snn_gemm_sk<HIDDEN><<<dim3(T_TOTAL / BM, 1), dim3(256), 0, stream>>>(hs, w, cur);
    }
    snn_scan_ov<<<dim3(NCHUNK), dim3(256), 0, stream>>>(cur, out);
}

// Round 12
// 76.169 us; speedup vs baseline: 1.8065x; 1.8065x over previous
//
#include <hip/hip_runtime.h>
#include <stdint.h>

#define HIDDEN 2048
#define EXPERTS 64
#define T_TOTAL 8192

// ================= GEMM: split-K, global_load_lds staged, 8x8 micro-tile =================
// EXACT R10 kernel (proven 40 us, VGPR=128, 0 conflicts, no spill). Occupancy comes from
// the dispatch: nsplit=32 -> grid 2048 blocks; LDS 24 KB -> 6 blocks/CU -> 12 waves/CU
// = 3 waves/SIMD (R10 was 2/SIMD). NO __launch_bounds__ min-waves arg (R11 lesson:
// (256,4) halved the VGPR cap to 64 -> 314 MB spill traffic).
#define BM 128

#define GLOAD16(g, l) __builtin_amdgcn_global_load_lds(                        \
        (const __attribute__((address_space(1))) unsigned int*)(g),            \
        (__attribute__((address_space(3))) unsigned int*)(l), 16, 0, 0)
#define FENCE() asm volatile("" ::: "memory")

template <int KS, int BK>
__global__ __launch_bounds__(128) void snn_gemm_sk(
        const float* __restrict__ A, const float* __restrict__ W,
        float* __restrict__ P) {
    __shared__ float As[2][BM * BK];
    __shared__ float Ws[2][BK * EXPERTS];

    constexpr int CB = BK / 4;       // 16B col-blocks per row
    constexpr int AR = BK / 4;       // A staging rounds (128 thr x 16B = 2 KB/round)
    constexpr int WR = BK / 8;       // W staging rounds
    constexpr int L  = AR + WR;      // loads in flight per stage

    const int t    = threadIdx.x;    // 0..127
    const int wv   = t >> 6;
    const int rg   = t >> 3;         // 0..15 : rows rg*8..rg*8+7
    const int eg   = t & 7;          // 0..7  : experts eg*8..eg*8+7
    const long row0 = (long)blockIdx.x * BM;
    const int  k0   = blockIdx.y * KS;
    float* Pout = P + (long)blockIdx.y * ((long)T_TOTAL * EXPERTS);

    // A staging: round p, LDS word = p*512 + wv*256 + lane*4:
    //   row = p*(512/BK) + t/CB, colblk = t&(CB-1); source col pre-swizzled by (row>>3).
    const float* aSrc[AR];
#pragma unroll
    for (int p = 0; p < AR; ++p) {
        const int row = p * (512 / BK) + t / CB;
        const int cb  = (t & (CB - 1)) ^ ((row >> 3) & (CB - 1));
        aSrc[p] = &A[(row0 + row) * HIDDEN + k0 + cb * 4];
    }
    // W staging: round p: k = p*8 + (t>>4), e4 = t&15. Linear both sides.
    const float* wSrc[WR];
#pragma unroll
    for (int p = 0; p < WR; ++p)
        wSrc[p] = &W[(long)(k0 + p * 8 + (t >> 4)) * EXPERTS + (t & 15) * 4];

    auto stage = [&](int tile, int buf) {
        const int  aoff = tile * BK;
        const long woff = (long)tile * BK * EXPERTS;
#pragma unroll
        for (int p = 0; p < AR; ++p)
            GLOAD16(aSrc[p] + aoff, &As[buf][p * 512 + wv * 256]);   // +lane*16B by HW
#pragma unroll
        for (int p = 0; p < WR; ++p)
            GLOAD16(wSrc[p] + woff, &Ws[buf][p * 512 + wv * 256]);
    };

    float acc[8][8];
#pragma unroll
    for (int i = 0; i < 8; ++i)
#pragma unroll
        for (int j = 0; j < 8; ++j) acc[i][j] = 0.0f;

    stage(0, 0);

    constexpr int NTILE = KS / BK;
    int buf = 0;
    for (int tile = 0; tile < NTILE; ++tile) {
        if (tile + 1 < NTILE) {
            stage(tile + 1, buf ^ 1);
            if constexpr (L == 6)  asm volatile("s_waitcnt vmcnt(6)" ::: "memory");
            else                   asm volatile("s_waitcnt vmcnt(12)" ::: "memory");
        } else {
            asm volatile("s_waitcnt vmcnt(0)" ::: "memory");
        }
        __builtin_amdgcn_s_barrier();
        FENCE();

        const float* ab = &As[buf][0];
        const float* wb = &Ws[buf][0];
        const int swz = rg & (CB - 1);   // == (row>>3)&(CB-1) for rows rg*8+i
#pragma unroll
        for (int q = 0; q < CB; ++q) {
            const int qs = (q ^ swz) * 4;
            float4 a4[8];
#pragma unroll
            for (int i = 0; i < 8; ++i)
                a4[i] = *reinterpret_cast<const float4*>(&ab[(rg * 8 + i) * BK + qs]);
#pragma unroll
            for (int ki = 0; ki < 4; ++ki) {   // k ascending: q outer, ki inner
                const float4 w0 = *reinterpret_cast<const float4*>(&wb[(q * 4 + ki) * EXPERTS + eg * 8]);
                const float4 w1 = *reinterpret_cast<const float4*>(&wb[(q * 4 + ki) * EXPERTS + eg * 8 + 4]);
#pragma unroll
                for (int i = 0; i < 8; ++i) {
                    const float av = (&a4[i].x)[ki];
                    acc[i][0] = fmaf(av, w0.x, acc[i][0]);
                    acc[i][1] = fmaf(av, w0.y, acc[i][1]);
                    acc[i][2] = fmaf(av, w0.z, acc[i][2]);
                    acc[i][3] = fmaf(av, w0.w, acc[i][3]);
                    acc[i][4] = fmaf(av, w1.x, acc[i][4]);
                    acc[i][5] = fmaf(av, w1.y, acc[i][5]);
                    acc[i][6] = fmaf(av, w1.z, acc[i][6]);
                    acc[i][7] = fmaf(av, w1.w, acc[i][7]);
                }
            }
        }
        FENCE();
        __builtin_amdgcn_s_barrier();   // all waves done with buf before restage
        buf ^= 1;
    }

#pragma unroll
    for (int i = 0; i < 8; ++i) {
        float* base = &Pout[(row0 + rg * 8 + i) * EXPERTS + eg * 8];
        *reinterpret_cast<float4*>(base)     = make_float4(acc[i][0], acc[i][1], acc[i][2], acc[i][3]);
        *reinterpret_cast<float4*>(base + 4) = make_float4(acc[i][4], acc[i][5], acc[i][6], acc[i][7]);
    }
}

// ---- fixed-order split-K combine (template-unrolled: loads issued in parallel) ----
template <int NS>
__global__ __launch_bounds__(256) void snn_combine(const float* __restrict__ P,
                                                   float* __restrict__ cur) {
    const long i = (long)blockIdx.x * 256 + threadIdx.x;   // float4 index
    const float4* p = reinterpret_cast<const float4*>(P);
    float4 s = p[i];
#pragma unroll
    for (int k = 1; k < NS; ++k) {
        const float4 v = p[i + (long)k * (T_TOTAL * EXPERTS / 4)];
        s.x += v.x; s.y += v.y; s.z += v.z; s.w += v.w;
    }
    reinterpret_cast<float4*>(cur)[i] = s;
}

// ========= Scan: zero-sync overlap (warm-up 256 steps) + fused softmax =========
// Block w computes steps [w*128-256, w*128+128) from zero state; 0.9^256 forgetting
// makes the output-window state exact (whp bitwise). No flags/states/fences.
#define NCHUNK 64
#define CSTEPS (T_TOTAL / NCHUNK)   // 128
#define WARM   256

template <bool STORE>
__device__ __forceinline__ void lif_chunk(const float (&cbuf)[32], float* __restrict__ smp,
                                          int orow, int e, float& mp, float& refr) {
#pragma clang fp contract(off)
#pragma unroll
    for (int j = 0; j < 32; ++j) {
        const float term   = (refr <= 0.0f) ? cbuf[j] : 0.0f;
        const float mp_pre = mp * 0.9f + term;
        if constexpr (STORE) smp[(orow + j) * EXPERTS + e] = mp_pre;
        const bool spike = mp_pre > 1.0f;
        mp = spike ? 0.0f : mp_pre;
        const float rdec = fmaxf(refr - 0.1f, 0.0f);
        refr = spike ? 1.0f : rdec;
    }
}

__global__ __launch_bounds__(256) void snn_scan_ov(const float* __restrict__ cur,
                                                   float* __restrict__ out) {
    __shared__ float smp[CSTEPS * EXPERTS];   // 32 KB
    const int tid = threadIdx.x;
    const int w   = blockIdx.x;

    if (tid < 64) {
        const int e     = tid;
        const int t0abs = w * CSTEPS;
        const int s0    = (t0abs >= WARM) ? (t0abs - WARM) : 0;
        const int nwarm = t0abs - s0;              // 0, 128 or 256 (mult of 32)
        const int cwarm = nwarm >> 5;
        const int nc    = cwarm + (CSTEPS >> 5);   // 4, 8 or 12 (even)
        const float* cb = cur + (long)s0 * EXPERTS + e;

        float mp = 0.0f, refr = 0.0f;
        float bufA[32], bufB[32];
#pragma unroll
        for (int j = 0; j < 32; ++j) bufA[j] = cb[j * EXPERTS] * 0.1f;

        for (int c2 = 0; c2 < nc; c2 += 2) {
            if (c2 + 1 < nc)
#pragma unroll
                for (int j = 0; j < 32; ++j) bufB[j] = cb[((c2 + 1) * 32 + j) * EXPERTS] * 0.1f;
            if (c2 >= cwarm) lif_chunk<true >(bufA, smp, c2 * 32 - nwarm, e, mp, refr);
            else             lif_chunk<false>(bufA, smp, 0, e, mp, refr);
            if (c2 + 2 < nc)
#pragma unroll
                for (int j = 0; j < 32; ++j) bufA[j] = cb[((c2 + 2) * 32 + j) * EXPERTS] * 0.1f;
            if (c2 + 1 >= cwarm) lif_chunk<true >(bufB, smp, (c2 + 1) * 32 - nwarm, e, mp, refr);
            else                 lif_chunk<false>(bufB, smp, 0, e, mp, refr);
        }
    }
    __syncthreads();

    // ---- fused routing softmax: wave wvid handles rows wvid*32 .. +31 ----
    const int lane = tid & 63;
    const int wvid = tid >> 6;
    const float em1 = expf(-1.0f);
#pragma unroll 4
    for (int r = wvid * 32; r < wvid * 32 + 32; ++r) {
        const float v = smp[r * EXPERTS + lane];
        const bool spike = v > 1.0f;
        const unsigned long long ball = __ballot(spike);
        float res;
        if (ball != 0ull) {
            const int n = __popcll(ball);
            const float denom = (float)n + (float)(EXPERTS - n) * em1;
            res = spike ? (1.0f / denom) : (em1 / denom);
        } else {
            float m = v;
#pragma unroll
            for (int off = 32; off >= 1; off >>= 1)
                m = fmaxf(m, __shfl_xor(m, off, 64));
            const float p = expf(v - m);
            float s = p;
#pragma unroll
            for (int off = 32; off >= 1; off >>= 1)
                s += __shfl_xor(s, off, 64);
            res = p / s;
        }
        out[((long)w * CSTEPS + r) * EXPERTS + lane] = res;
    }
}

// ---------------------------------------------------------------------------
extern "C" void kernel_launch(void* const* d_in, const int* in_sizes, int n_in,
                              void* d_out, int out_size, void* d_ws, size_t ws_size,
                              hipStream_t stream) {
    const float* hs = (const float*)d_in[0];   // [4,2048,2048] f32
    const float* w  = (const float*)d_in[1];   // [2048,64] f32
    float* out = (float*)d_out;                // [4,2048,64] f32

    char*  ws   = (char*)d_ws;
    float* cur  = (float*)(ws + (1u << 20));   // 2 MB @ 1 MB
    float* part = (float*)(ws + (4u << 20));   // up to 32 x 2 MB @ 4 MB

    const size_t slab = (size_t)T_TOTAL * EXPERTS * sizeof(float);   // 2 MB

    if (ws_size >= (4u << 20) + 32 * slab) {            // 68 MB (R10 evidence: ws ~262 MB)
        snn_gemm_sk<HIDDEN / 32, 16><<<dim3(T_TOTAL / BM, 32), dim3(128), 0, stream>>>(hs, w, part);
        snn_combine<32><<<dim3(T_TOTAL * EXPERTS / 4 / 256), dim3(256), 0, stream>>>(part, cur);
    } else if (ws_size >= (4u << 20) + 16 * slab) {
        snn_gemm_sk<HIDDEN / 16, 16><<<dim3(T_TOTAL / BM, 16), dim3(128), 0, stream>>>(hs, w, part);
        snn_combine<16><<<dim3(T_TOTAL * EXPERTS / 4 / 256), dim3(256), 0, stream>>>(part, cur);
    } else if (ws_size >= (4u << 20) + 8 * slab) {
        snn_gemm_sk<HIDDEN / 8, 32><<<dim3(T_TOTAL / BM, 8), dim3(128), 0, stream>>>(hs, w, part);
        snn_combine<8><<<dim3(T_TOTAL * EXPERTS / 4 / 256), dim3(256), 0, stream>>>(part, cur);
    } else {
        snn_gemm_sk<HIDDEN, 32><<<dim3(T_TOTAL / BM, 1), dim3(128), 0, stream>>>(hs, w, cur);
    }
    snn_scan_ov<<<dim3(NCHUNK), dim3(256), 0, stream>>>(cur, out);
}